// Round 6
// baseline (330.813 us; speedup 1.0000x reference)
//
#include <hip/hip_runtime.h>
#include <math.h>

typedef unsigned short u16;
typedef unsigned int u32;
typedef __bf16 bf16x8 __attribute__((ext_vector_type(8)));
typedef float f32x4 __attribute__((ext_vector_type(4)));

__device__ __forceinline__ float bf2f(u16 v){ union{u32 u;float f;}c; c.u=((u32)v)<<16; return c.f; }
__device__ __forceinline__ u16 f2bf(float f){ union{__bf16 h; u16 u;}c; c.h=(__bf16)f; return c.u; }
__device__ __forceinline__ u32 pk2(float a, float b){
  union{ __bf16 h[2]; u32 u; }c; c.h[0]=(__bf16)a; c.h[1]=(__bf16)b; return c.u;
}
// load 8 consecutive f32 (32B-aligned) -> 8 bf16 packed in uint4
__device__ __forceinline__ uint4 ld8f(const float* p){
  float4 x = ((const float4*)p)[0];
  float4 y = ((const float4*)p)[1];
  uint4 r; r.x=pk2(x.x,x.y); r.y=pk2(x.z,x.w); r.z=pk2(y.x,y.y); r.w=pk2(y.z,y.w);
  return r;
}
__device__ __forceinline__ bf16x8 u4tob(uint4 v){ union{uint4 u; bf16x8 b;}c; c.u=v; return c.b; }
// silu via v_rcp_f32 (1-ulp) instead of IEEE divide
__device__ __forceinline__ float fsilu(float x){
  return x*__builtin_amdgcn_rcpf(1.f+__expf(-x));
}

// ---------------- fused setup kernel ----------------
// ranges: [0,nb0) edges | [nb0,nb1) out_ptr | [nb1,nb2) compact W | [nb2,nb3) smallw |
//         [nb3,nb4) h_bf | [nb4,..) rbf2p
__global__ void k_setup_all(const int* __restrict__ e1_to_e2,
                            const float* __restrict__ rbf_e1,
                            const float* __restrict__ sph_e1,
                            u16* __restrict__ rbf1p, float* __restrict__ sph_c, int E1,
                            const int* __restrict__ src2, int* __restrict__ out_ptr,
                            int Nn, int E2,
                            const float* __restrict__ w1,
                            u16* __restrict__ W0T, u16* __restrict__ W1T,
                            u16* __restrict__ W2T,
                            const float* __restrict__ w2, const float* __restrict__ wgw,
                            const float* __restrict__ wgt, const float* __restrict__ b2,
                            u16* __restrict__ WcT, u16* __restrict__ WgtT,
                            float* __restrict__ bc2,
                            const float* __restrict__ h, u16* __restrict__ h_bf,
                            const float* __restrict__ rbf_e2, u16* __restrict__ rbf2p,
                            int nb0, int nb1, int nb2, int nb3, int nb4) {
  const int b = blockIdx.x, t = threadIdx.x;
  if (b < nb0) {
    int e = b*256 + t;
    if (e >= E1) return;
    int f = e1_to_e2[e];
    sph_c[f] = sph_e1[e*3+1];
    const float* s = rbf_e1 + (size_t)e*32;
    uint4* d = (uint4*)(rbf1p + (size_t)f*32);
    d[0]=ld8f(s); d[1]=ld8f(s+8); d[2]=ld8f(s+16); d[3]=ld8f(s+24);
  } else if (b < nb1) {
    int n = (b-nb0)*256 + t;
    if (n > Nn) return;
    int lo=0, hi=E2;
    while (lo<hi){ int m=(lo+hi)>>1; if (src2[m]<n) lo=m+1; else hi=m; }
    out_ptr[n]=lo;
  } else if (b < nb2) {
    // compact transposed weights:
    // W0T[128][416]: t1 | h_i | h_k | rbf1_ik   (w1 rows 0,384,512,768)
    // W1T[128][288]: t2 | h_j | rbf1_kj         (rows 128,640,800)
    // W2T[128][160]: t3 | rbf2                   (rows 256,832)
    int id = (b-nb1)*256 + t;
    if (id < 128*416) {
      int n = id/416, k = id - n*416;
      int row = (k<128)? k : (k<256)? 384+(k-128) : (k<384)? 512+(k-256) : 768+(k-384);
      W0T[id] = f2bf(w1[row*128+n]);
    } else if (id < 128*(416+288)) {
      int id2 = id - 128*416;
      int n = id2/288, k = id2 - n*288;
      int row = (k<128)? 128+k : (k<256)? 640+(k-128) : 800+(k-256);
      W1T[id2] = f2bf(w1[row*128+n]);
    } else if (id < 128*864) {
      int id2 = id - 128*704;
      int n = id2/160, k = id2 - n*160;
      int row = (k<128)? 256+k : 832+(k-128);
      W2T[id2] = f2bf(w1[row*128+n]);
    }
  } else if (b < nb3) {
    int id = (b-nb2)*256 + t;
    if (id < 16384) {
      int n = id&127, k = id>>7;
      float s = 0.f;
      for (int r=0;r<128;r++) s += w2[k*128+r]*wgw[r*128+n];
      WcT[n*128+k] = f2bf(s);
      WgtT[n*128+k] = f2bf(wgt[k*128+n]);
    } else if (id < 16384+128) {
      int n = id-16384;
      float s = 0.f;
      for (int r=0;r<128;r++) s += b2[r]*wgw[r*128+n];
      bc2[n] = s;
    }
  } else if (b < nb4) {
    int id = (b-nb3)*256 + t;            // Nn*16 threads, 8 elems each
    if (id < Nn*16) ((uint4*)h_bf)[id] = ld8f(h + (size_t)id*8);
  } else {
    int id = (b-nb4)*256 + t;            // E2*4 threads, 8 elems each
    if (id < E2*4) ((uint4*)rbf2p)[id] = ld8f(rbf_e2 + (size_t)id*8);
  }
}

// ---------------- fused wedge enumeration + accumulation (round-4 proven) ----------------
__global__ __launch_bounds__(256, 8)
void k_wedge(const int* __restrict__ src2, const int* __restrict__ dst2,
             const int* __restrict__ out_ptr, const float* __restrict__ sph_c,
             const u16* __restrict__ Q1, const u16* __restrict__ Q2,
             const u16* __restrict__ P3, const float* __restrict__ w1,
             u16* __restrict__ S, int* __restrict__ cnt, int E2) {
  int gw = (int)((blockIdx.x*256 + threadIdx.x) >> 6);
  int lane = threadIdx.x & 63;
  if (gw >= E2) return;
  int i = src2[gw], j = dst2[gw];
  int f = 0, lo = 0; float cf = 0.f; bool valid = false;
  if (lane < 8) {
    int ff = out_ptr[i] + lane;
    if (ff < out_ptr[i+1]) {
      int k = dst2[ff];
      int l = out_ptr[k], hh = out_ptr[k+1], h0 = hh;
      while (l<hh){ int m=(l+hh)>>1; if (dst2[m]<j) l=m+1; else hh=m; }
      if (l<h0 && dst2[l]==j){ valid=true; f=ff; lo=l; cf=sph_c[ff]*sph_c[l]; }
    }
  }
  unsigned long long mask = __ballot(valid);
  const int nw = __popcll(mask);
  if (lane==0) cnt[gw] = nw;
  u32 p3u = ((const u32*)(P3 + (size_t)gw*128))[lane];
  float p30 = bf2f((u16)(p3u&0xffff)), p31 = bf2f((u16)(p3u>>16));
  float2 wv = ((const float2*)(w1 + 864*128))[lane];
  const u32* q1b = (const u32*)Q1;
  const u32* q2b = (const u32*)Q2;

  // ISSUE phase: readlane broadcast + all gather loads in flight
  u32 xa[8], ya[8]; float ca[8];
  unsigned long long m2 = mask;
  #pragma unroll
  for (int s=0; s<8; s++) {
    if (s < nw) {
      int b = __ffsll((long long)m2)-1; m2 &= m2-1;
      int fA = __builtin_amdgcn_readlane(f, b);
      int lA = __builtin_amdgcn_readlane(lo, b);
      ca[s] = __int_as_float(__builtin_amdgcn_readlane(__float_as_int(cf), b));
      xa[s] = q1b[((size_t)(u32)fA<<6) + lane];
      ya[s] = q2b[((size_t)(u32)lA<<6) + lane];
    }
  }

  // COMPUTE phase
  float a0=0.f, a1=0.f;
  #pragma unroll
  for (int s=0; s<8; s++) {
    if (s < nw) {
      float b0 = fmaf(ca[s], wv.x, p30);
      float b1 = fmaf(ca[s], wv.y, p31);
      float x0 = b0 + bf2f((u16)(xa[s]&0xffff)) + bf2f((u16)(ya[s]&0xffff));
      float x1 = b1 + bf2f((u16)(xa[s]>>16))    + bf2f((u16)(ya[s]>>16));
      a0 += fsilu(x0);
      a1 += fsilu(x1);
    }
  }
  ((u32*)(S + (size_t)gw*128))[lane] = pk2(a0, a1);
}

// ---------------- GEMM args ----------------
struct GArgs {
  const float* t_f32; const u16* h_bf; const u16* rbf2p;
  const u16* rbf1p; const u16* Asrc;
  const int* src2; const int* dst2; const int* cnt;
  const u16* B0; const u16* B1; const u16* B2;
  const u16* Bmat; const u16* Bmat2;
  const float* b1; const float* bgw; const float* bgt; const float* bc2;
  u16* out0; u16* out1; u16* out2;
  float* outf;
  int M;
};

// A-fragment load for big GEMM (fully unrolled -> ks constant-folds)
template<int BN>
__device__ __forceinline__ bf16x8 ldAfrag(const GArgs& a, int ks, long row,
                                          int hs_, int hd_, int off) {
  if (ks<4) return u4tob(ld8f(a.t_f32 + row*128 + ks*32 + off));
  if (BN==0) {
    if (ks<8)  return *(const bf16x8*)(a.h_bf + (long)hs_*128 + (ks-4)*32 + off);
    if (ks<12) return *(const bf16x8*)(a.h_bf + (long)hd_*128 + (ks-8)*32 + off);
    return *(const bf16x8*)(a.rbf1p + row*32 + off);
  } else if (BN==1) {
    if (ks<8)  return *(const bf16x8*)(a.h_bf + (long)hd_*128 + (ks-4)*32 + off);
    return *(const bf16x8*)(a.rbf1p + row*32 + off);
  } else {
    return *(const bf16x8*)(a.rbf2p + row*32 + off);
  }
}

// ---------------- big GEMM: LDS-free, barrier-free, K-specialized per bn ----------------
// Each wave loads its MFMA fragments directly from global (B is L2-resident,
// A rows as 16B/lane). No __syncthreads -> no vmcnt(0) drain; compiler overlaps
// step k+1 loads with step k MFMAs; ~10 waves/CU never synchronize.
template<int BN>
__device__ __forceinline__ void gemm0_body(const GArgs& a, int bm,
                                           int wm, int wn, int quad, int l16) {
  constexpr int NK = (BN==0)?13:((BN==1)?9:5);
  constexpr int KT = NK*32;
  const int off = quad*8;
  long rowA[4]; int hs[4], hd[4]; const u16* bp[4];
  const u16* Bp = (BN==0)? a.B0 : (BN==1)? a.B1 : a.B2;
  #pragma unroll
  for (int t=0;t<4;t++) {
    long r = (long)bm*128 + wm*64 + t*16 + l16; if (r >= a.M) r = a.M-1;
    rowA[t]=r;
    hs[t] = (BN==0)? a.src2[r] : 0;
    hd[t] = (BN<2)?  a.dst2[r] : 0;
    bp[t] = Bp + (long)(wn*64 + t*16 + l16)*KT + off;
  }
  f32x4 acc[4][4] = {};
  bf16x8 A0[4], B0v[4], A1[4], B1v[4];

  #pragma unroll
  for (int t=0;t<4;t++) { A0[t]=ldAfrag<BN>(a,0,rowA[t],hs[t],hd[t],off);
                          B0v[t]=*(const bf16x8*)(bp[t]); }
  #pragma unroll
  for (int ks=0; ks<NK; ks++) {
    if ((ks&1)==0) {
      if (ks+1<NK) {
        #pragma unroll
        for (int t=0;t<4;t++){ A1[t]=ldAfrag<BN>(a,ks+1,rowA[t],hs[t],hd[t],off);
                               B1v[t]=*(const bf16x8*)(bp[t]+(ks+1)*32); }
      }
      #pragma unroll
      for (int tm=0;tm<4;tm++)
        #pragma unroll
        for (int tn=0;tn<4;tn++)
          acc[tm][tn] = __builtin_amdgcn_mfma_f32_16x16x32_bf16(A0[tm], B0v[tn], acc[tm][tn], 0,0,0);
    } else {
      if (ks+1<NK) {
        #pragma unroll
        for (int t=0;t<4;t++){ A0[t]=ldAfrag<BN>(a,ks+1,rowA[t],hs[t],hd[t],off);
                               B0v[t]=*(const bf16x8*)(bp[t]+(ks+1)*32); }
      }
      #pragma unroll
      for (int tm=0;tm<4;tm++)
        #pragma unroll
        for (int tn=0;tn<4;tn++)
          acc[tm][tn] = __builtin_amdgcn_mfma_f32_16x16x32_bf16(A1[tm], B1v[tn], acc[tm][tn], 0,0,0);
    }
  }

  // epilogue (C/D: col=lane&15, row=quad*4+reg)
  u16* dst = (BN==0)? a.out0 : (BN==1)? a.out1 : a.out2;
  #pragma unroll
  for (int tm=0;tm<4;tm++) {
    const int rloc = wm*64 + tm*16 + quad*4;
    #pragma unroll
    for (int r=0;r<4;r++) {
      long row = (long)bm*128 + rloc + r;
      if (row >= a.M) continue;
      #pragma unroll
      for (int tn=0;tn<4;tn++) {
        const int col = wn*64 + tn*16 + l16;
        float v = acc[tm][tn][r];
        if (BN==2) v += a.b1[col];
        dst[row*128 + col] = f2bf(v);
      }
    }
  }
}

__global__ __launch_bounds__(256, 2)
void k_gemm0(GArgs a) {
  const int nwg = gridDim.x;
  const int id  = blockIdx.x;
  const int xcd = id & 7, idx = id >> 3;
  const int q = nwg >> 3, r = nwg & 7;
  const int w = (xcd < r ? xcd*(q+1) : r*(q+1) + (xcd-r)*q) + idx;
  const int bm = w/3, bn = w - bm*3;
  const int tid = threadIdx.x;
  const int lane = tid & 63, wave = tid >> 6;
  const int wm = wave >> 1, wn = wave & 1;
  const int quad = lane >> 4, l16 = lane & 15;
  if (bn==0)      gemm0_body<0>(a, bm, wm, wn, quad, l16);
  else if (bn==1) gemm0_body<1>(a, bm, wm, wn, quad, l16);
  else            gemm0_body<2>(a, bm, wm, wn, quad, l16);
}

// ---------------- fused gate GEMMs: LDS-free, barrier-free ----------------
__global__ __launch_bounds__(256, 2)
void k_gemm12(GArgs a) {
  const int bm = blockIdx.x;
  const int tid = threadIdx.x;
  const int lane = tid & 63, wave = tid >> 6;
  const int wm = wave >> 1, wn = wave & 1;
  const int quad = lane >> 4, l16 = lane & 15;
  const int off = quad*8;

  long rowA[4]; const u16 *bc[4], *bg[4];
  #pragma unroll
  for (int t=0;t<4;t++) {
    long r = (long)bm*128 + wm*64 + t*16 + l16; if (r >= a.M) r = a.M-1;
    rowA[t]=r;
    long rowB = (long)(wn*64 + t*16 + l16)*128;
    bc[t] = a.Bmat  + rowB + off;
    bg[t] = a.Bmat2 + rowB + off;
  }
  f32x4 acc1[4][4] = {};
  f32x4 acc2[4][4] = {};

  // pass 1: S @ WcT
  #pragma unroll
  for (int ks=0; ks<4; ks++) {
    bf16x8 af[4], bfr[4];
    #pragma unroll
    for (int t=0;t<4;t++) {
      af[t]  = *(const bf16x8*)(a.Asrc + rowA[t]*128 + ks*32 + off);
      bfr[t] = *(const bf16x8*)(bc[t] + ks*32);
    }
    #pragma unroll
    for (int tm=0;tm<4;tm++)
      #pragma unroll
      for (int tn=0;tn<4;tn++)
        acc1[tm][tn] = __builtin_amdgcn_mfma_f32_16x16x32_bf16(af[tm], bfr[tn], acc1[tm][tn], 0,0,0);
  }
  // pass 2: bf16(t) @ WgtT
  #pragma unroll
  for (int ks=0; ks<4; ks++) {
    bf16x8 af[4], bfr[4];
    #pragma unroll
    for (int t=0;t<4;t++) {
      af[t]  = u4tob(ld8f(a.t_f32 + rowA[t]*128 + ks*32 + off));
      bfr[t] = *(const bf16x8*)(bg[t] + ks*32);
    }
    #pragma unroll
    for (int tm=0;tm<4;tm++)
      #pragma unroll
      for (int tn=0;tn<4;tn++)
        acc2[tm][tn] = __builtin_amdgcn_mfma_f32_16x16x32_bf16(af[tm], bfr[tn], acc2[tm][tn], 0,0,0);
  }

  // combined epilogue (rcp-based sigmoid/tanh; 1-ulp, within tolerance)
  #pragma unroll
  for (int tm=0;tm<4;tm++) {
    const int rloc = wm*64 + tm*16 + quad*4;
    #pragma unroll
    for (int r=0;r<4;r++) {
      long row = (long)bm*128 + rloc + r;
      if (row >= a.M) continue;
      #pragma unroll
      for (int tn=0;tn<4;tn++) {
        const int col = wn*64 + tn*16 + l16;
        float u = acc1[tm][tn][r] + (float)a.cnt[row]*a.bc2[col] + a.bgw[col];
        float g = __builtin_amdgcn_rcpf(1.f+__expf(-u));
        float vv = acc2[tm][tn][r] + a.bgt[col];
        float th = 1.f - 2.f*__builtin_amdgcn_rcpf(__expf(2.f*vv)+1.f);
        float t  = a.t_f32[row*128+col];
        a.outf[row*128+col] = t + g*th;
      }
    }
  }
}

// ---------------- launch ----------------
extern "C" void kernel_launch(void* const* d_in, const int* in_sizes, int n_in,
                              void* d_out, int out_size, void* d_ws, size_t ws_size,
                              hipStream_t stream) {
  const float* t_e2  = (const float*)d_in[0];
  const float* h     = (const float*)d_in[1];
  const int* ei2     = (const int*)d_in[3];
  const int* e1_to_e2 = (const int*)d_in[4];
  const float* rbf_e1 = (const float*)d_in[7];
  const float* rbf_e2 = (const float*)d_in[8];
  const float* sph_e1 = (const float*)d_in[9];
  const float* w1  = (const float*)d_in[11];
  const float* b1  = (const float*)d_in[12];
  const float* w2  = (const float*)d_in[13];
  const float* b2  = (const float*)d_in[14];
  const float* wgw = (const float*)d_in[15];
  const float* bgw = (const float*)d_in[16];
  const float* wgt = (const float*)d_in[17];
  const float* bgt = (const float*)d_in[18];

  const int E2 = in_sizes[0]/128;
  const int Nn = in_sizes[1]/128;
  const int E1 = in_sizes[5];
  const int* src2 = ei2;
  const int* dst2 = ei2 + E2;

  // workspace carve (16B-aligned regions, ~75 MB)
  char* p = (char*)d_ws;
  u16* Q1 = (u16*)p;       p += (size_t)E2*128*2;
  u16* Q2 = (u16*)p;       p += (size_t)E2*128*2;
  u16* P3 = (u16*)p;       p += (size_t)E2*128*2;   // aliased as S after wedge
  u16* rbf1p = (u16*)p;    p += (size_t)E2*32*2;
  u16* rbf2p = (u16*)p;    p += (size_t)E2*32*2;
  u16* h_bf  = (u16*)p;    p += (size_t)Nn*128*2;
  u16* W0T = (u16*)p;      p += (size_t)128*416*2;
  u16* W1T = (u16*)p;      p += (size_t)128*288*2;
  u16* W2T = (u16*)p;      p += (size_t)128*160*2;
  u16* WcT   = (u16*)p;    p += (size_t)128*128*2;
  u16* WgtT  = (u16*)p;    p += (size_t)128*128*2;
  float* sph_c = (float*)p; p += (size_t)E2*4;
  float* bc2   = (float*)p; p += 512;
  int* out_ptr = (int*)p;   p += (((size_t)(Nn+1)*4 + 63)/64)*64;
  int* cnt     = (int*)p;   p += (size_t)E2*4;
  u16* S = P3;   // alias: safe (row-local read-then-write in k_wedge)

  // fused setup: block-range dispatch
  const int nb_edges = (E1+255)/256;
  const int nb_ptr   = (Nn+1+255)/256;
  const int nb_w     = (128*864+255)/256;
  const int nb_small = (16512+255)/256;
  const int nb_hbf   = (Nn*16+255)/256;
  const int nb_rbf2  = (E2*4+255)/256;
  const int nb0 = nb_edges;
  const int nb1 = nb0 + nb_ptr;
  const int nb2 = nb1 + nb_w;
  const int nb3 = nb2 + nb_small;
  const int nb4 = nb3 + nb_hbf;
  const int nbT = nb4 + nb_rbf2;
  k_setup_all<<<nbT, 256, 0, stream>>>(e1_to_e2, rbf_e1, sph_e1, rbf1p, sph_c, E1,
                                       src2, out_ptr, Nn, E2,
                                       w1, W0T, W1T, W2T,
                                       w2, wgw, wgt, b2,
                                       WcT, WgtT, bc2,
                                       h, h_bf, rbf_e2, rbf2p,
                                       nb0, nb1, nb2, nb3, nb4);

  const int Mb = (E2+127)/128;
  {
    GArgs a = {};
    a.t_f32=t_e2; a.h_bf=h_bf; a.rbf1p=rbf1p; a.rbf2p=rbf2p;
    a.src2=src2; a.dst2=dst2;
    a.B0=W0T; a.B1=W1T; a.B2=W2T; a.b1=b1;
    a.out0=Q1; a.out1=Q2; a.out2=P3; a.M=E2;
    k_gemm0<<<Mb*3, 256, 0, stream>>>(a);
  }
  k_wedge<<<(E2+3)/4, 256, 0, stream>>>(src2, dst2, out_ptr, sph_c,
                                        Q1, Q2, P3, w1, S, cnt, E2);
  {
    GArgs a = {};
    a.Asrc=S; a.cnt=cnt; a.Bmat=WcT; a.Bmat2=WgtT;
    a.bgw=bgw; a.bgt=bgt; a.bc2=bc2; a.t_f32=t_e2;
    a.outf=(float*)d_out; a.M=E2;
    k_gemm12<<<Mb, 256, 0, stream>>>(a);
  }
}

// Round 8
// 329.367 us; speedup vs baseline: 1.0044x; 1.0044x over previous
//
#include <hip/hip_runtime.h>
#include <math.h>

typedef unsigned short u16;
typedef unsigned int u32;
typedef __bf16 bf16x8 __attribute__((ext_vector_type(8)));
typedef float f32x4 __attribute__((ext_vector_type(4)));

__device__ __forceinline__ float bf2f(u16 v){ union{u32 u;float f;}c; c.u=((u32)v)<<16; return c.f; }
__device__ __forceinline__ u16 f2bf(float f){ union{__bf16 h; u16 u;}c; c.h=(__bf16)f; return c.u; }
__device__ __forceinline__ u32 pk2(float a, float b){
  union{ __bf16 h[2]; u32 u; }c; c.h[0]=(__bf16)a; c.h[1]=(__bf16)b; return c.u;
}
// load 8 consecutive f32 (32B-aligned) -> 8 bf16 packed in uint4
__device__ __forceinline__ uint4 ld8f(const float* p){
  float4 x = ((const float4*)p)[0];
  float4 y = ((const float4*)p)[1];
  uint4 r; r.x=pk2(x.x,x.y); r.y=pk2(x.z,x.w); r.z=pk2(y.x,y.y); r.w=pk2(y.z,y.w);
  return r;
}
// silu via v_rcp_f32 (1-ulp) instead of IEEE divide
__device__ __forceinline__ float fsilu(float x){
  return x*__builtin_amdgcn_rcpf(1.f+__expf(-x));
}

// ---------------- fused setup kernel ----------------
// ranges: [0,nb0) edges | [nb0,nb1) out_ptr | [nb1,nb2) weights | [nb2,..) smallw
// Wall layout (u16):
//   [0)      W0T[128][160]: k<128 -> w1 row k     (t1) | k>=128 -> 768+(k-128) (rbf1_ik)
//   [20480)  W1T[128][160]: k<128 -> 128+k        (t2) | k>=128 -> 800+(k-128) (rbf1_kj)
//   [40960)  W2T[128][160]: k<128 -> 256+k        (t3) | k>=128 -> 832+(k-128) (rbf2)
//   [61440)  WHiT[128][128]: [n][k] = w1[(384+k)*128+n]
//   [77824)  WHkT[128][128]: [n][k] = w1[(512+k)*128+n]
//   [94208)  WHjT[128][128]: [n][k] = w1[(640+k)*128+n]
__global__ void k_setup_all(const int* __restrict__ e1_to_e2,
                            const float* __restrict__ rbf_e1,
                            const float* __restrict__ sph_e1,
                            u16* __restrict__ rbf1p, float* __restrict__ sph_c, int E1,
                            const int* __restrict__ src2, int* __restrict__ out_ptr,
                            int Nn, int E2,
                            const float* __restrict__ w1, u16* __restrict__ Wall,
                            const float* __restrict__ w2, const float* __restrict__ wgw,
                            const float* __restrict__ wgt, const float* __restrict__ b2,
                            u16* __restrict__ WcT, u16* __restrict__ WgtT,
                            float* __restrict__ bc2,
                            int nb0, int nb1, int nb2) {
  const int b = blockIdx.x, t = threadIdx.x;
  if (b < nb0) {
    int e = b*256 + t;
    if (e >= E1) return;
    int f = e1_to_e2[e];
    sph_c[f] = sph_e1[e*3+1];
    const float* s = rbf_e1 + (size_t)e*32;
    uint4* d = (uint4*)(rbf1p + (size_t)f*32);
    d[0]=ld8f(s); d[1]=ld8f(s+8); d[2]=ld8f(s+16); d[3]=ld8f(s+24);
  } else if (b < nb1) {
    int n = (b-nb0)*256 + t;
    if (n > Nn) return;
    int lo=0, hi=E2;
    while (lo<hi){ int m=(lo+hi)>>1; if (src2[m]<n) lo=m+1; else hi=m; }
    out_ptr[n]=lo;
  } else if (b < nb2) {
    int id = (b-nb1)*256 + t;
    if (id < 61440) {
      int m = id / 20480;
      int r2 = id - m*20480;
      int n = r2 / 160, k = r2 - n*160;
      int row;
      if (m==0)      row = (k<128)? k       : 768+(k-128);
      else if (m==1) row = (k<128)? 128+k   : 800+(k-128);
      else           row = (k<128)? 256+k   : 832+(k-128);
      Wall[id] = f2bf(w1[row*128+n]);
    } else if (id < 110592) {
      int idh = id - 61440;
      int m = idh >> 14;            // 0..2
      int r2 = idh & 16383;
      int n = r2 >> 7, k = r2 & 127;
      int base = 384 + m*128;
      Wall[id] = f2bf(w1[(base+k)*128+n]);
    }
  } else {
    int id = (b-nb2)*256 + t;
    if (id < 16384) {
      int n = id&127, k = id>>7;
      float s = 0.f;
      for (int r=0;r<128;r++) s += w2[k*128+r]*wgw[r*128+n];
      WcT[n*128+k] = f2bf(s);
      WgtT[n*128+k] = f2bf(wgt[k*128+n]);
    } else if (id < 16384+128) {
      int n = id-16384;
      float s = 0.f;
      for (int r=0;r<128;r++) s += b2[r]*wgw[r*128+n];
      bc2[n] = s;
    }
  }
}

// ---------------- per-node h projection: H{i,k,j} = h @ WH{i,k,j} ----------------
__global__ __launch_bounds__(256, 2)
void k_gemmH(const float* __restrict__ h, const u16* __restrict__ WH,
             u16* __restrict__ Hout, int Nn) {
  const int bm = blockIdx.x, bn = blockIdx.y;
  const u16* Bp = WH + bn*16384;
  u16* dst = Hout + (size_t)bn*Nn*128;
  __shared__ u16 As[128*40];
  __shared__ u16 Bs[128*40];
  const int tid = threadIdx.x;
  const int lane = tid & 63, wave = tid >> 6;
  const int wm = wave >> 1, wn = wave & 1;
  const int quad = lane >> 4, l16 = lane & 15;
  const int part = tid & 3;
  const int ra = tid >> 2;
  const int rb = ra + 64;
  long fa = (long)bm*128 + ra; if (fa >= Nn) fa = Nn-1;
  long fb = (long)bm*128 + rb; if (fb >= Nn) fb = Nn-1;

  f32x4 acc[4][4] = {};
  for (int ks=0; ks<4; ks++) {
    const int kb = ks*32;
    uint4 va = ld8f(h + fa*128 + kb + part*8);
    uint4 vb = ld8f(h + fb*128 + kb + part*8);
    uint4 wa = *(const uint4*)(Bp + (long)ra*128 + kb + part*8);
    uint4 wb = *(const uint4*)(Bp + (long)rb*128 + kb + part*8);
    __syncthreads();
    *(uint4*)(As + ra*40 + part*8) = va;
    *(uint4*)(As + rb*40 + part*8) = vb;
    *(uint4*)(Bs + ra*40 + part*8) = wa;
    *(uint4*)(Bs + rb*40 + part*8) = wb;
    __syncthreads();
    bf16x8 af[4], bfr[4];
    #pragma unroll
    for (int t=0;t<4;t++) {
      af[t]  = *(const bf16x8*)(As + (wm*64 + t*16 + l16)*40 + quad*8);
      bfr[t] = *(const bf16x8*)(Bs + (wn*64 + t*16 + l16)*40 + quad*8);
    }
    #pragma unroll
    for (int tm=0;tm<4;tm++)
      #pragma unroll
      for (int tn=0;tn<4;tn++)
        acc[tm][tn] = __builtin_amdgcn_mfma_f32_16x16x32_bf16(af[tm], bfr[tn], acc[tm][tn], 0,0,0);
  }
  #pragma unroll
  for (int tm=0;tm<4;tm++) {
    const int rloc = wm*64 + tm*16 + quad*4;
    #pragma unroll
    for (int r=0;r<4;r++) {
      long row = (long)bm*128 + rloc + r;
      if (row >= Nn) continue;
      #pragma unroll
      for (int tn=0;tn<4;tn++) {
        const int col = wn*64 + tn*16 + l16;
        dst[row*128 + col] = f2bf(acc[tm][tn][r]);
      }
    }
  }
}

// ---------------- fused wedge enumeration + accumulation (round-4 proven) ----------------
__global__ __launch_bounds__(256, 8)
void k_wedge(const int* __restrict__ src2, const int* __restrict__ dst2,
             const int* __restrict__ out_ptr, const float* __restrict__ sph_c,
             const u16* __restrict__ Q1, const u16* __restrict__ Q2,
             const u16* __restrict__ P3, const float* __restrict__ w1,
             u16* __restrict__ S, int* __restrict__ cnt, int E2) {
  int gw = (int)((blockIdx.x*256 + threadIdx.x) >> 6);
  int lane = threadIdx.x & 63;
  if (gw >= E2) return;
  int i = src2[gw], j = dst2[gw];
  int f = 0, lo = 0; float cf = 0.f; bool valid = false;
  if (lane < 8) {
    int ff = out_ptr[i] + lane;
    if (ff < out_ptr[i+1]) {
      int k = dst2[ff];
      int l = out_ptr[k], hh = out_ptr[k+1], h0 = hh;
      while (l<hh){ int m=(l+hh)>>1; if (dst2[m]<j) l=m+1; else hh=m; }
      if (l<h0 && dst2[l]==j){ valid=true; f=ff; lo=l; cf=sph_c[ff]*sph_c[l]; }
    }
  }
  unsigned long long mask = __ballot(valid);
  const int nw = __popcll(mask);
  if (lane==0) cnt[gw] = nw;
  u32 p3u = ((const u32*)(P3 + (size_t)gw*128))[lane];
  float p30 = bf2f((u16)(p3u&0xffff)), p31 = bf2f((u16)(p3u>>16));
  float2 wv = ((const float2*)(w1 + 864*128))[lane];
  const u32* q1b = (const u32*)Q1;
  const u32* q2b = (const u32*)Q2;

  // ISSUE phase: readlane broadcast + all gather loads in flight
  u32 xa[8], ya[8]; float ca[8];
  unsigned long long m2 = mask;
  #pragma unroll
  for (int s=0; s<8; s++) {
    if (s < nw) {
      int b = __ffsll((long long)m2)-1; m2 &= m2-1;
      int fA = __builtin_amdgcn_readlane(f, b);
      int lA = __builtin_amdgcn_readlane(lo, b);
      ca[s] = __int_as_float(__builtin_amdgcn_readlane(__float_as_int(cf), b));
      xa[s] = q1b[((size_t)(u32)fA<<6) + lane];
      ya[s] = q2b[((size_t)(u32)lA<<6) + lane];
    }
  }

  // COMPUTE phase
  float a0=0.f, a1=0.f;
  #pragma unroll
  for (int s=0; s<8; s++) {
    if (s < nw) {
      float b0 = fmaf(ca[s], wv.x, p30);
      float b1 = fmaf(ca[s], wv.y, p31);
      float x0 = b0 + bf2f((u16)(xa[s]&0xffff)) + bf2f((u16)(ya[s]&0xffff));
      float x1 = b1 + bf2f((u16)(xa[s]>>16))    + bf2f((u16)(ya[s]>>16));
      a0 += fsilu(x0);
      a1 += fsilu(x1);
    }
  }
  ((u32*)(S + (size_t)gw*128))[lane] = pk2(a0, a1);
}

// ---------------- GEMM args ----------------
struct GArgs {
  const float* t_f32; const float* rbf_e2;
  const u16* rbf1p; const u16* Asrc;
  const int* src2; const int* dst2; const int* cnt;
  const u16* B0; const u16* B1; const u16* B2;
  const u16* Hi; const u16* Hk; const u16* Hj;
  const u16* Bmat; const u16* Bmat2;
  const float* b1; const float* bgw; const float* bgt; const float* bc2;
  u16* out0; u16* out1; u16* out2;
  float* outf;
  int M;
};

// ---------------- big GEMM: uniform K=160, H gather-add epilogue ----------------
// bn=0: [t|rbf1]@W0 + Hi[src]+Hk[dst] -> Q1
// bn=1: [t|rbf1]@W1 + Hj[dst]         -> Q2
// bn=2: [t|rbf2]@W2 + b1              -> P3
__global__ __launch_bounds__(256, 2)
void k_gemm0(GArgs a) {
  const int nwg = gridDim.x;
  const int id  = blockIdx.x;
  const int xcd = id & 7, idx = id >> 3;
  const int q = nwg >> 3, r = nwg & 7;
  const int w = (xcd < r ? xcd*(q+1) : r*(q+1) + (xcd-r)*q) + idx;
  const int bm = w/3, bn = w - bm*3;

  __shared__ u16 sm[32768];          // 64 KB: GEMM bufs (20 KB) then H staging
  u16* As = sm;
  u16* Bs = sm + 5120;
  const int tid = threadIdx.x;
  const int lane = tid & 63, wave = tid >> 6;
  const int wm = wave >> 1, wn = wave & 1;
  const int quad = lane >> 4, l16 = lane & 15;

  const int part = tid & 3;        // k-subchunk (8 elems)
  const int ra = tid >> 2;
  const int rb = ra + 64;
  long fa = (long)bm*128 + ra;
  long fb = (long)bm*128 + rb;
  if (fa >= a.M) fa = a.M-1;
  if (fb >= a.M) fb = a.M-1;

  const u16* Bp = (bn==0)? a.B0 : (bn==1)? a.B1 : a.B2;
  constexpr int KT = 160;

  f32x4 acc[4][4] = {};
  for (int ks=0; ks<5; ks++) {
    const int kb = ks*32;
    uint4 va, vb;
    if (ks<4)        { va = ld8f(a.t_f32 + fa*128 + kb + part*8);
                       vb = ld8f(a.t_f32 + fb*128 + kb + part*8); }
    else if (bn<2)   { va = *(const uint4*)(a.rbf1p + fa*32 + part*8);
                       vb = *(const uint4*)(a.rbf1p + fb*32 + part*8); }
    else             { va = ld8f(a.rbf_e2 + fa*32 + part*8);
                       vb = ld8f(a.rbf_e2 + fb*32 + part*8); }
    uint4 wa = *(const uint4*)(Bp + (long)ra*KT + kb + part*8);
    uint4 wb = *(const uint4*)(Bp + (long)rb*KT + kb + part*8);
    __syncthreads();
    *(uint4*)(As + ra*40 + part*8) = va;
    *(uint4*)(As + rb*40 + part*8) = vb;
    *(uint4*)(Bs + ra*40 + part*8) = wa;
    *(uint4*)(Bs + rb*40 + part*8) = wb;
    __syncthreads();
    bf16x8 af[4], bfr[4];
    #pragma unroll
    for (int t=0;t<4;t++) {
      af[t]  = *(const bf16x8*)(As + (wm*64 + t*16 + l16)*40 + quad*8);
      bfr[t] = *(const bf16x8*)(Bs + (wn*64 + t*16 + l16)*40 + quad*8);
    }
    #pragma unroll
    for (int tm=0;tm<4;tm++)
      #pragma unroll
      for (int tn=0;tn<4;tn++)
        acc[tm][tn] = __builtin_amdgcn_mfma_f32_16x16x32_bf16(af[tm], bfr[tn], acc[tm][tn], 0,0,0);
  }

  // H staging into LDS (bn<2): sm[0..16383]=first H, sm[16384..32767]=second H
  // 128 rows x 128 bf16 = 2048 chunks of 16B -> 8 iters x 256 threads.
  if (bn < 2) {
    __syncthreads();   // all ds_reads of As/Bs done before overwrite
    #pragma unroll
    for (int c=0;c<8;c++) {
      int idx2 = tid + c*256;           // [0,2048): row=idx>>4, 16B chunk=idx&15
      int row = idx2 >> 4, ch = idx2 & 15;
      long fr = (long)bm*128 + row;
      if (fr >= a.M) fr = a.M-1;
      if (bn==0) {
        int s = a.src2[fr], d = a.dst2[fr];
        *(uint4*)(&sm[row*128 + ch*8])         = *(const uint4*)(a.Hi + (long)s*128 + ch*8);
        *(uint4*)(&sm[16384 + row*128 + ch*8]) = *(const uint4*)(a.Hk + (long)d*128 + ch*8);
      } else {
        int d = a.dst2[fr];
        *(uint4*)(&sm[row*128 + ch*8])         = *(const uint4*)(a.Hj + (long)d*128 + ch*8);
      }
    }
    __syncthreads();
  }

  // epilogue (C/D: col=lane&15, row=quad*4+reg)
  u16* dst = (bn==0)? a.out0 : (bn==1)? a.out1 : a.out2;
  #pragma unroll
  for (int tm=0;tm<4;tm++) {
    const int rloc = wm*64 + tm*16 + quad*4;
    #pragma unroll
    for (int r=0;r<4;r++) {
      long row = (long)bm*128 + rloc + r;
      if (row >= a.M) continue;
      const int rl = rloc + r;
      #pragma unroll
      for (int tn=0;tn<4;tn++) {
        const int col = wn*64 + tn*16 + l16;
        float v = acc[tm][tn][r];
        if (bn==0)      v += bf2f(sm[rl*128+col]) + bf2f(sm[16384+rl*128+col]);
        else if (bn==1) v += bf2f(sm[rl*128+col]);
        else            v += a.b1[col];
        dst[row*128 + col] = f2bf(v);
      }
    }
  }
}

// ---------------- fused gate GEMMs (round-4 proven structure) ----------------
__global__ __launch_bounds__(256, 2)
void k_gemm12(GArgs a) {
  __shared__ u16 As[128*40];
  __shared__ u16 Bs[128*40];
  const int tid = threadIdx.x;
  const int bm = blockIdx.x;
  const int lane = tid & 63, wave = tid >> 6;
  const int wm = wave >> 1, wn = wave & 1;
  const int quad = lane >> 4, l16 = lane & 15;

  const int part = tid & 3;
  const int ra = tid >> 2;
  const int rb = ra + 64;
  long fa = (long)bm*128 + ra;
  long fb = (long)bm*128 + rb;
  if (fa >= a.M) fa = a.M-1;
  if (fb >= a.M) fb = a.M-1;

  f32x4 acc1[4][4] = {};
  f32x4 acc2[4][4] = {};
  // pass 1: S @ WcT
  for (int ks=0; ks<4; ks++) {
    const int kb = ks*32;
    uint4 va = *(const uint4*)(a.Asrc + fa*128 + kb + part*8);
    uint4 vb = *(const uint4*)(a.Asrc + fb*128 + kb + part*8);
    uint4 wa = *(const uint4*)(a.Bmat + (long)ra*128 + kb + part*8);
    uint4 wbv= *(const uint4*)(a.Bmat + (long)rb*128 + kb + part*8);
    __syncthreads();
    *(uint4*)(As + ra*40 + part*8) = va;
    *(uint4*)(As + rb*40 + part*8) = vb;
    *(uint4*)(Bs + ra*40 + part*8) = wa;
    *(uint4*)(Bs + rb*40 + part*8) = wbv;
    __syncthreads();
    bf16x8 af[4], bfr[4];
    #pragma unroll
    for (int t=0;t<4;t++) {
      af[t]  = *(const bf16x8*)(As + (wm*64 + t*16 + l16)*40 + quad*8);
      bfr[t] = *(const bf16x8*)(Bs + (wn*64 + t*16 + l16)*40 + quad*8);
    }
    #pragma unroll
    for (int tm=0;tm<4;tm++)
      #pragma unroll
      for (int tn=0;tn<4;tn++)
        acc1[tm][tn] = __builtin_amdgcn_mfma_f32_16x16x32_bf16(af[tm], bfr[tn], acc1[tm][tn], 0,0,0);
  }
  // pass 2: bf16(t) @ WgtT
  for (int ks=0; ks<4; ks++) {
    const int kb = ks*32;
    uint4 va = ld8f(a.t_f32 + fa*128 + kb + part*8);
    uint4 vb = ld8f(a.t_f32 + fb*128 + kb + part*8);
    uint4 wa = *(const uint4*)(a.Bmat2 + (long)ra*128 + kb + part*8);
    uint4 wbv= *(const uint4*)(a.Bmat2 + (long)rb*128 + kb + part*8);
    __syncthreads();
    *(uint4*)(As + ra*40 + part*8) = va;
    *(uint4*)(As + rb*40 + part*8) = vb;
    *(uint4*)(Bs + ra*40 + part*8) = wa;
    *(uint4*)(Bs + rb*40 + part*8) = wbv;
    __syncthreads();
    bf16x8 af[4], bfr[4];
    #pragma unroll
    for (int t=0;t<4;t++) {
      af[t]  = *(const bf16x8*)(As + (wm*64 + t*16 + l16)*40 + quad*8);
      bfr[t] = *(const bf16x8*)(Bs + (wn*64 + t*16 + l16)*40 + quad*8);
    }
    #pragma unroll
    for (int tm=0;tm<4;tm++)
      #pragma unroll
      for (int tn=0;tn<4;tn++)
        acc2[tm][tn] = __builtin_amdgcn_mfma_f32_16x16x32_bf16(af[tm], bfr[tn], acc2[tm][tn], 0,0,0);
  }

  // combined epilogue (rcp-based sigmoid/tanh; 1-ulp, within tolerance)
  #pragma unroll
  for (int tm=0;tm<4;tm++) {
    const int rloc = wm*64 + tm*16 + quad*4;
    #pragma unroll
    for (int r=0;r<4;r++) {
      long row = (long)bm*128 + rloc + r;
      if (row >= a.M) continue;
      #pragma unroll
      for (int tn=0;tn<4;tn++) {
        const int col = wn*64 + tn*16 + l16;
        float u = acc1[tm][tn][r] + (float)a.cnt[row]*a.bc2[col] + a.bgw[col];
        float g = __builtin_amdgcn_rcpf(1.f+__expf(-u));
        float vv = acc2[tm][tn][r] + a.bgt[col];
        float th = 1.f - 2.f*__builtin_amdgcn_rcpf(__expf(2.f*vv)+1.f);
        float t  = a.t_f32[row*128+col];
        a.outf[row*128+col] = t + g*th;
      }
    }
  }
}

// ---------------- launch ----------------
extern "C" void kernel_launch(void* const* d_in, const int* in_sizes, int n_in,
                              void* d_out, int out_size, void* d_ws, size_t ws_size,
                              hipStream_t stream) {
  const float* t_e2  = (const float*)d_in[0];
  const float* h     = (const float*)d_in[1];
  const int* ei2     = (const int*)d_in[3];
  const int* e1_to_e2 = (const int*)d_in[4];
  const float* rbf_e1 = (const float*)d_in[7];
  const float* rbf_e2 = (const float*)d_in[8];
  const float* sph_e1 = (const float*)d_in[9];
  const float* w1  = (const float*)d_in[11];
  const float* b1  = (const float*)d_in[12];
  const float* w2  = (const float*)d_in[13];
  const float* b2  = (const float*)d_in[14];
  const float* wgw = (const float*)d_in[15];
  const float* bgw = (const float*)d_in[16];
  const float* wgt = (const float*)d_in[17];
  const float* bgt = (const float*)d_in[18];

  const int E2 = in_sizes[0]/128;
  const int Nn = in_sizes[1]/128;
  const int E1 = in_sizes[5];
  const int* src2 = ei2;
  const int* dst2 = ei2 + E2;

  // workspace carve (16B-aligned regions, ~76 MB)
  char* p = (char*)d_ws;
  u16* Q1 = (u16*)p;       p += (size_t)E2*128*2;
  u16* Q2 = (u16*)p;       p += (size_t)E2*128*2;
  u16* P3 = (u16*)p;       p += (size_t)E2*128*2;   // aliased as S after wedge
  u16* rbf1p = (u16*)p;    p += (size_t)E2*32*2;
  u16* Hout  = (u16*)p;    p += (size_t)3*Nn*128*2; // Hi | Hk | Hj
  u16* Wall  = (u16*)p;    p += (size_t)110592*2;
  u16* WcT   = (u16*)p;    p += (size_t)128*128*2;
  u16* WgtT  = (u16*)p;    p += (size_t)128*128*2;
  float* sph_c = (float*)p; p += (size_t)E2*4;
  float* bc2   = (float*)p; p += 512;
  int* out_ptr = (int*)p;   p += (((size_t)(Nn+1)*4 + 63)/64)*64;
  int* cnt     = (int*)p;   p += (size_t)E2*4;
  u16* S = P3;   // alias: safe (row-local read-then-write in k_wedge)
  u16* Hi = Hout, *Hk = Hout + (size_t)Nn*128, *Hj = Hout + (size_t)2*Nn*128;

  // fused setup: block-range dispatch
  const int nb_edges = (E1+255)/256;
  const int nb_ptr   = (Nn+1+255)/256;
  const int nb_w     = (110592+255)/256;
  const int nb_small = (16512+255)/256;
  const int nb0 = nb_edges;
  const int nb1 = nb0 + nb_ptr;
  const int nb2 = nb1 + nb_w;
  const int nbT = nb2 + nb_small;
  k_setup_all<<<nbT, 256, 0, stream>>>(e1_to_e2, rbf_e1, sph_e1, rbf1p, sph_c, E1,
                                       src2, out_ptr, Nn, E2,
                                       w1, Wall, w2, wgw, wgt, b2,
                                       WcT, WgtT, bc2,
                                       nb0, nb1, nb2);

  const int Mh = (Nn+127)/128;
  k_gemmH<<<dim3(Mh,3), 256, 0, stream>>>(h, Wall + 61440, Hout, Nn);

  const int Mb = (E2+127)/128;
  {
    GArgs a = {};
    a.t_f32=t_e2; a.rbf_e2=rbf_e2; a.rbf1p=rbf1p;
    a.src2=src2; a.dst2=dst2;
    a.B0=Wall; a.B1=Wall+20480; a.B2=Wall+40960;
    a.Hi=Hi; a.Hk=Hk; a.Hj=Hj; a.b1=b1;
    a.out0=Q1; a.out1=Q2; a.out2=P3; a.M=E2;
    k_gemm0<<<Mb*3, 256, 0, stream>>>(a);
  }
  k_wedge<<<(E2+3)/4, 256, 0, stream>>>(src2, dst2, out_ptr, sph_c,
                                        Q1, Q2, P3, w1, S, cnt, E2);
  {
    GArgs a = {};
    a.Asrc=S; a.cnt=cnt; a.Bmat=WcT; a.Bmat2=WgtT;
    a.bgw=bgw; a.bgt=bgt; a.bc2=bc2; a.t_f32=t_e2;
    a.outf=(float*)d_out; a.M=E2;
    k_gemm12<<<Mb, 256, 0, stream>>>(a);
  }
}

// Round 9
// 316.228 us; speedup vs baseline: 1.0461x; 1.0416x over previous
//
#include <hip/hip_runtime.h>
#include <math.h>

typedef unsigned short u16;
typedef unsigned int u32;
typedef __bf16 bf16x8 __attribute__((ext_vector_type(8)));
typedef float f32x4 __attribute__((ext_vector_type(4)));

__device__ __forceinline__ float bf2f(u16 v){ union{u32 u;float f;}c; c.u=((u32)v)<<16; return c.f; }
__device__ __forceinline__ u16 f2bf(float f){ union{__bf16 h; u16 u;}c; c.h=(__bf16)f; return c.u; }
__device__ __forceinline__ u32 pk2(float a, float b){
  union{ __bf16 h[2]; u32 u; }c; c.h[0]=(__bf16)a; c.h[1]=(__bf16)b; return c.u;
}
// load 8 consecutive f32 (32B-aligned) -> 8 bf16 packed in uint4
__device__ __forceinline__ uint4 ld8f(const float* p){
  float4 x = ((const float4*)p)[0];
  float4 y = ((const float4*)p)[1];
  uint4 r; r.x=pk2(x.x,x.y); r.y=pk2(x.z,x.w); r.z=pk2(y.x,y.y); r.w=pk2(y.z,y.w);
  return r;
}
// silu via v_rcp_f32 (1-ulp) instead of IEEE divide
__device__ __forceinline__ float fsilu(float x){
  return x*__builtin_amdgcn_rcpf(1.f+__expf(-x));
}

// ---------------- fused setup kernel ----------------
// ranges: [0,nb0) edges | [nb0,nb1) out_ptr | [nb1,nb2) weights | [nb2,..) smallw
// Wall layout (u16):
//   [0)      W0T[128][160]: k<128 -> w1 row k     (t1) | k>=128 -> 768+(k-128) (rbf1_ik)
//   [20480)  W1T[128][160]: k<128 -> 128+k        (t2) | k>=128 -> 800+(k-128) (rbf1_kj)
//   [40960)  W2T[128][160]: k<128 -> 256+k        (t3) | k>=128 -> 832+(k-128) (rbf2)
//   [61440)  WHiT[128][128]: [n][k] = w1[(384+k)*128+n]
//   [77824)  WHkT[128][128]: [n][k] = w1[(512+k)*128+n]
//   [94208)  WHjT[128][128]: [n][k] = w1[(640+k)*128+n]
__global__ void k_setup_all(const int* __restrict__ e1_to_e2,
                            const float* __restrict__ rbf_e1,
                            const float* __restrict__ sph_e1,
                            u16* __restrict__ rbf1p, float* __restrict__ sph_c, int E1,
                            const int* __restrict__ src2, int* __restrict__ out_ptr,
                            int Nn, int E2,
                            const float* __restrict__ w1, u16* __restrict__ Wall,
                            const float* __restrict__ w2, const float* __restrict__ wgw,
                            const float* __restrict__ wgt, const float* __restrict__ b2,
                            u16* __restrict__ WcT, u16* __restrict__ WgtT,
                            float* __restrict__ bc2,
                            int nb0, int nb1, int nb2) {
  const int b = blockIdx.x, t = threadIdx.x;
  if (b < nb0) {
    int e = b*256 + t;
    if (e >= E1) return;
    int f = e1_to_e2[e];
    sph_c[f] = sph_e1[e*3+1];
    const float* s = rbf_e1 + (size_t)e*32;
    uint4* d = (uint4*)(rbf1p + (size_t)f*32);
    d[0]=ld8f(s); d[1]=ld8f(s+8); d[2]=ld8f(s+16); d[3]=ld8f(s+24);
  } else if (b < nb1) {
    int n = (b-nb0)*256 + t;
    if (n > Nn) return;
    int lo=0, hi=E2;
    while (lo<hi){ int m=(lo+hi)>>1; if (src2[m]<n) lo=m+1; else hi=m; }
    out_ptr[n]=lo;
  } else if (b < nb2) {
    int id = (b-nb1)*256 + t;
    if (id < 61440) {
      int m = id / 20480;
      int r2 = id - m*20480;
      int n = r2 / 160, k = r2 - n*160;
      int row;
      if (m==0)      row = (k<128)? k       : 768+(k-128);
      else if (m==1) row = (k<128)? 128+k   : 800+(k-128);
      else           row = (k<128)? 256+k   : 832+(k-128);
      Wall[id] = f2bf(w1[row*128+n]);
    } else if (id < 110592) {
      int idh = id - 61440;
      int m = idh >> 14;            // 0..2
      int r2 = idh & 16383;
      int n = r2 >> 7, k = r2 & 127;
      int base = 384 + m*128;
      Wall[id] = f2bf(w1[(base+k)*128+n]);
    }
  } else {
    int id = (b-nb2)*256 + t;
    if (id < 16384) {
      int n = id&127, k = id>>7;
      float s = 0.f;
      for (int r=0;r<128;r++) s += w2[k*128+r]*wgw[r*128+n];
      WcT[n*128+k] = f2bf(s);
      WgtT[n*128+k] = f2bf(wgt[k*128+n]);
    } else if (id < 16384+128) {
      int n = id-16384;
      float s = 0.f;
      for (int r=0;r<128;r++) s += b2[r]*wgw[r*128+n];
      bc2[n] = s;
    }
  }
}

// ---------------- per-node h projection: H{i,k,j} = h @ WH{i,k,j} ----------------
__global__ __launch_bounds__(256, 2)
void k_gemmH(const float* __restrict__ h, const u16* __restrict__ WH,
             u16* __restrict__ Hout, int Nn) {
  const int bm = blockIdx.x, bn = blockIdx.y;
  const u16* Bp = WH + bn*16384;
  u16* dst = Hout + (size_t)bn*Nn*128;
  __shared__ u16 As[128*40];
  __shared__ u16 Bs[128*40];
  const int tid = threadIdx.x;
  const int lane = tid & 63, wave = tid >> 6;
  const int wm = wave >> 1, wn = wave & 1;
  const int quad = lane >> 4, l16 = lane & 15;
  const int part = tid & 3;
  const int ra = tid >> 2;
  const int rb = ra + 64;
  long fa = (long)bm*128 + ra; if (fa >= Nn) fa = Nn-1;
  long fb = (long)bm*128 + rb; if (fb >= Nn) fb = Nn-1;

  f32x4 acc[4][4] = {};
  for (int ks=0; ks<4; ks++) {
    const int kb = ks*32;
    uint4 va = ld8f(h + fa*128 + kb + part*8);
    uint4 vb = ld8f(h + fb*128 + kb + part*8);
    uint4 wa = *(const uint4*)(Bp + (long)ra*128 + kb + part*8);
    uint4 wb = *(const uint4*)(Bp + (long)rb*128 + kb + part*8);
    __syncthreads();
    *(uint4*)(As + ra*40 + part*8) = va;
    *(uint4*)(As + rb*40 + part*8) = vb;
    *(uint4*)(Bs + ra*40 + part*8) = wa;
    *(uint4*)(Bs + rb*40 + part*8) = wb;
    __syncthreads();
    bf16x8 af[4], bfr[4];
    #pragma unroll
    for (int t=0;t<4;t++) {
      af[t]  = *(const bf16x8*)(As + (wm*64 + t*16 + l16)*40 + quad*8);
      bfr[t] = *(const bf16x8*)(Bs + (wn*64 + t*16 + l16)*40 + quad*8);
    }
    #pragma unroll
    for (int tm=0;tm<4;tm++)
      #pragma unroll
      for (int tn=0;tn<4;tn++)
        acc[tm][tn] = __builtin_amdgcn_mfma_f32_16x16x32_bf16(af[tm], bfr[tn], acc[tm][tn], 0,0,0);
  }
  #pragma unroll
  for (int tm=0;tm<4;tm++) {
    const int rloc = wm*64 + tm*16 + quad*4;
    #pragma unroll
    for (int r=0;r<4;r++) {
      long row = (long)bm*128 + rloc + r;
      if (row >= Nn) continue;
      #pragma unroll
      for (int tn=0;tn<4;tn++) {
        const int col = wn*64 + tn*16 + l16;
        dst[row*128 + col] = f2bf(acc[tm][tn][r]);
      }
    }
  }
}

// ---------------- fused wedge enumeration + accumulation (round-4 proven) ----------------
__global__ __launch_bounds__(256, 8)
void k_wedge(const int* __restrict__ src2, const int* __restrict__ dst2,
             const int* __restrict__ out_ptr, const float* __restrict__ sph_c,
             const u16* __restrict__ Q1, const u16* __restrict__ Q2,
             const u16* __restrict__ P3, const float* __restrict__ w1,
             u16* __restrict__ S, int* __restrict__ cnt, int E2) {
  int gw = (int)((blockIdx.x*256 + threadIdx.x) >> 6);
  int lane = threadIdx.x & 63;
  if (gw >= E2) return;
  int i = src2[gw], j = dst2[gw];
  int f = 0, lo = 0; float cf = 0.f; bool valid = false;
  if (lane < 8) {
    int ff = out_ptr[i] + lane;
    if (ff < out_ptr[i+1]) {
      int k = dst2[ff];
      int l = out_ptr[k], hh = out_ptr[k+1], h0 = hh;
      while (l<hh){ int m=(l+hh)>>1; if (dst2[m]<j) l=m+1; else hh=m; }
      if (l<h0 && dst2[l]==j){ valid=true; f=ff; lo=l; cf=sph_c[ff]*sph_c[l]; }
    }
  }
  unsigned long long mask = __ballot(valid);
  const int nw = __popcll(mask);
  if (lane==0) cnt[gw] = nw;
  u32 p3u = ((const u32*)(P3 + (size_t)gw*128))[lane];
  float p30 = bf2f((u16)(p3u&0xffff)), p31 = bf2f((u16)(p3u>>16));
  float2 wv = ((const float2*)(w1 + 864*128))[lane];
  const u32* q1b = (const u32*)Q1;
  const u32* q2b = (const u32*)Q2;

  // ISSUE phase: readlane broadcast + all gather loads in flight
  u32 xa[8], ya[8]; float ca[8];
  unsigned long long m2 = mask;
  #pragma unroll
  for (int s=0; s<8; s++) {
    if (s < nw) {
      int b = __ffsll((long long)m2)-1; m2 &= m2-1;
      int fA = __builtin_amdgcn_readlane(f, b);
      int lA = __builtin_amdgcn_readlane(lo, b);
      ca[s] = __int_as_float(__builtin_amdgcn_readlane(__float_as_int(cf), b));
      xa[s] = q1b[((size_t)(u32)fA<<6) + lane];
      ya[s] = q2b[((size_t)(u32)lA<<6) + lane];
    }
  }

  // COMPUTE phase
  float a0=0.f, a1=0.f;
  #pragma unroll
  for (int s=0; s<8; s++) {
    if (s < nw) {
      float b0 = fmaf(ca[s], wv.x, p30);
      float b1 = fmaf(ca[s], wv.y, p31);
      float x0 = b0 + bf2f((u16)(xa[s]&0xffff)) + bf2f((u16)(ya[s]&0xffff));
      float x1 = b1 + bf2f((u16)(xa[s]>>16))    + bf2f((u16)(ya[s]>>16));
      a0 += fsilu(x0);
      a1 += fsilu(x1);
    }
  }
  ((u32*)(S + (size_t)gw*128))[lane] = pk2(a0, a1);
}

// ---------------- GEMM args ----------------
struct GArgs {
  const float* t_f32; const float* rbf_e2;
  const u16* rbf1p; const u16* Asrc;
  const int* src2; const int* dst2; const int* cnt;
  const u16* B0; const u16* B1; const u16* B2;
  const u16* Hi; const u16* Hk; const u16* Hj;
  const u16* Bmat; const u16* Bmat2;
  const float* b1; const float* bgw; const float* bgt; const float* bc2;
  u16* out0; u16* out1; u16* out2;
  float* outf;
  int M;
};

// ---------------- big GEMM: uniform K=160, H gather-add epilogue ----------------
// bn=0: [t|rbf1]@W0 + Hi[src]+Hk[dst] -> Q1
// bn=1: [t|rbf1]@W1 + Hj[dst]         -> Q2
// bn=2: [t|rbf2]@W2 + b1              -> P3
// Round-4 proven 2-barrier staged main loop, 20 KB LDS (occupancy-preserving).
// H-add reads directly from global: H matrices are 2.5 MB each (L2/L3-resident),
// 16 lanes read 16 consecutive u16 = one 32B segment per quad-row -> coalesced.
__global__ __launch_bounds__(256, 2)
void k_gemm0(GArgs a) {
  const int nwg = gridDim.x;
  const int id  = blockIdx.x;
  const int xcd = id & 7, idx = id >> 3;
  const int q = nwg >> 3, r = nwg & 7;
  const int w = (xcd < r ? xcd*(q+1) : r*(q+1) + (xcd-r)*q) + idx;
  const int bm = w/3, bn = w - bm*3;

  __shared__ u16 As[128*40];
  __shared__ u16 Bs[128*40];
  const int tid = threadIdx.x;
  const int lane = tid & 63, wave = tid >> 6;
  const int wm = wave >> 1, wn = wave & 1;
  const int quad = lane >> 4, l16 = lane & 15;

  const int part = tid & 3;        // k-subchunk (8 elems)
  const int ra = tid >> 2;
  const int rb = ra + 64;
  long fa = (long)bm*128 + ra;
  long fb = (long)bm*128 + rb;
  if (fa >= a.M) fa = a.M-1;
  if (fb >= a.M) fb = a.M-1;

  const u16* Bp = (bn==0)? a.B0 : (bn==1)? a.B1 : a.B2;
  constexpr int KT = 160;

  f32x4 acc[4][4] = {};
  for (int ks=0; ks<5; ks++) {
    const int kb = ks*32;
    uint4 va, vb;
    if (ks<4)        { va = ld8f(a.t_f32 + fa*128 + kb + part*8);
                       vb = ld8f(a.t_f32 + fb*128 + kb + part*8); }
    else if (bn<2)   { va = *(const uint4*)(a.rbf1p + fa*32 + part*8);
                       vb = *(const uint4*)(a.rbf1p + fb*32 + part*8); }
    else             { va = ld8f(a.rbf_e2 + fa*32 + part*8);
                       vb = ld8f(a.rbf_e2 + fb*32 + part*8); }
    uint4 wa = *(const uint4*)(Bp + (long)ra*KT + kb + part*8);
    uint4 wb = *(const uint4*)(Bp + (long)rb*KT + kb + part*8);
    __syncthreads();
    *(uint4*)(As + ra*40 + part*8) = va;
    *(uint4*)(As + rb*40 + part*8) = vb;
    *(uint4*)(Bs + ra*40 + part*8) = wa;
    *(uint4*)(Bs + rb*40 + part*8) = wb;
    __syncthreads();
    bf16x8 af[4], bfr[4];
    #pragma unroll
    for (int t=0;t<4;t++) {
      af[t]  = *(const bf16x8*)(As + (wm*64 + t*16 + l16)*40 + quad*8);
      bfr[t] = *(const bf16x8*)(Bs + (wn*64 + t*16 + l16)*40 + quad*8);
    }
    #pragma unroll
    for (int tm=0;tm<4;tm++)
      #pragma unroll
      for (int tn=0;tn<4;tn++)
        acc[tm][tn] = __builtin_amdgcn_mfma_f32_16x16x32_bf16(af[tm], bfr[tn], acc[tm][tn], 0,0,0);
  }

  // epilogue (C/D: col=lane&15, row=quad*4+reg), H-add direct from global
  u16* dst = (bn==0)? a.out0 : (bn==1)? a.out1 : a.out2;
  #pragma unroll
  for (int tm=0;tm<4;tm++) {
    const int rloc = wm*64 + tm*16 + quad*4;
    #pragma unroll
    for (int r=0;r<4;r++) {
      long row = (long)bm*128 + rloc + r;
      if (row >= a.M) continue;
      const u16 *hA = nullptr, *hB = nullptr;
      if (bn==0)      { hA = a.Hi + (long)a.src2[row]*128;
                        hB = a.Hk + (long)a.dst2[row]*128; }
      else if (bn==1) { hA = a.Hj + (long)a.dst2[row]*128; }
      #pragma unroll
      for (int tn=0;tn<4;tn++) {
        const int col = wn*64 + tn*16 + l16;
        float v = acc[tm][tn][r];
        if (bn==0)      v += bf2f(hA[col]) + bf2f(hB[col]);
        else if (bn==1) v += bf2f(hA[col]);
        else            v += a.b1[col];
        dst[row*128 + col] = f2bf(v);
      }
    }
  }
}

// ---------------- fused gate GEMMs (round-4 proven structure) ----------------
__global__ __launch_bounds__(256, 2)
void k_gemm12(GArgs a) {
  __shared__ u16 As[128*40];
  __shared__ u16 Bs[128*40];
  const int tid = threadIdx.x;
  const int bm = blockIdx.x;
  const int lane = tid & 63, wave = tid >> 6;
  const int wm = wave >> 1, wn = wave & 1;
  const int quad = lane >> 4, l16 = lane & 15;

  const int part = tid & 3;
  const int ra = tid >> 2;
  const int rb = ra + 64;
  long fa = (long)bm*128 + ra;
  long fb = (long)bm*128 + rb;
  if (fa >= a.M) fa = a.M-1;
  if (fb >= a.M) fb = a.M-1;

  f32x4 acc1[4][4] = {};
  f32x4 acc2[4][4] = {};
  // pass 1: S @ WcT
  for (int ks=0; ks<4; ks++) {
    const int kb = ks*32;
    uint4 va = *(const uint4*)(a.Asrc + fa*128 + kb + part*8);
    uint4 vb = *(const uint4*)(a.Asrc + fb*128 + kb + part*8);
    uint4 wa = *(const uint4*)(a.Bmat + (long)ra*128 + kb + part*8);
    uint4 wbv= *(const uint4*)(a.Bmat + (long)rb*128 + kb + part*8);
    __syncthreads();
    *(uint4*)(As + ra*40 + part*8) = va;
    *(uint4*)(As + rb*40 + part*8) = vb;
    *(uint4*)(Bs + ra*40 + part*8) = wa;
    *(uint4*)(Bs + rb*40 + part*8) = wbv;
    __syncthreads();
    bf16x8 af[4], bfr[4];
    #pragma unroll
    for (int t=0;t<4;t++) {
      af[t]  = *(const bf16x8*)(As + (wm*64 + t*16 + l16)*40 + quad*8);
      bfr[t] = *(const bf16x8*)(Bs + (wn*64 + t*16 + l16)*40 + quad*8);
    }
    #pragma unroll
    for (int tm=0;tm<4;tm++)
      #pragma unroll
      for (int tn=0;tn<4;tn++)
        acc1[tm][tn] = __builtin_amdgcn_mfma_f32_16x16x32_bf16(af[tm], bfr[tn], acc1[tm][tn], 0,0,0);
  }
  // pass 2: bf16(t) @ WgtT
  for (int ks=0; ks<4; ks++) {
    const int kb = ks*32;
    uint4 va = ld8f(a.t_f32 + fa*128 + kb + part*8);
    uint4 vb = ld8f(a.t_f32 + fb*128 + kb + part*8);
    uint4 wa = *(const uint4*)(a.Bmat2 + (long)ra*128 + kb + part*8);
    uint4 wbv= *(const uint4*)(a.Bmat2 + (long)rb*128 + kb + part*8);
    __syncthreads();
    *(uint4*)(As + ra*40 + part*8) = va;
    *(uint4*)(As + rb*40 + part*8) = vb;
    *(uint4*)(Bs + ra*40 + part*8) = wa;
    *(uint4*)(Bs + rb*40 + part*8) = wbv;
    __syncthreads();
    bf16x8 af[4], bfr[4];
    #pragma unroll
    for (int t=0;t<4;t++) {
      af[t]  = *(const bf16x8*)(As + (wm*64 + t*16 + l16)*40 + quad*8);
      bfr[t] = *(const bf16x8*)(Bs + (wn*64 + t*16 + l16)*40 + quad*8);
    }
    #pragma unroll
    for (int tm=0;tm<4;tm++)
      #pragma unroll
      for (int tn=0;tn<4;tn++)
        acc2[tm][tn] = __builtin_amdgcn_mfma_f32_16x16x32_bf16(af[tm], bfr[tn], acc2[tm][tn], 0,0,0);
  }

  // combined epilogue (rcp-based sigmoid/tanh; 1-ulp, within tolerance)
  #pragma unroll
  for (int tm=0;tm<4;tm++) {
    const int rloc = wm*64 + tm*16 + quad*4;
    #pragma unroll
    for (int r=0;r<4;r++) {
      long row = (long)bm*128 + rloc + r;
      if (row >= a.M) continue;
      #pragma unroll
      for (int tn=0;tn<4;tn++) {
        const int col = wn*64 + tn*16 + l16;
        float u = acc1[tm][tn][r] + (float)a.cnt[row]*a.bc2[col] + a.bgw[col];
        float g = __builtin_amdgcn_rcpf(1.f+__expf(-u));
        float vv = acc2[tm][tn][r] + a.bgt[col];
        float th = 1.f - 2.f*__builtin_amdgcn_rcpf(__expf(2.f*vv)+1.f);
        float t  = a.t_f32[row*128+col];
        a.outf[row*128+col] = t + g*th;
      }
    }
  }
}

// ---------------- launch ----------------
extern "C" void kernel_launch(void* const* d_in, const int* in_sizes, int n_in,
                              void* d_out, int out_size, void* d_ws, size_t ws_size,
                              hipStream_t stream) {
  const float* t_e2  = (const float*)d_in[0];
  const float* h     = (const float*)d_in[1];
  const int* ei2     = (const int*)d_in[3];
  const int* e1_to_e2 = (const int*)d_in[4];
  const float* rbf_e1 = (const float*)d_in[7];
  const float* rbf_e2 = (const float*)d_in[8];
  const float* sph_e1 = (const float*)d_in[9];
  const float* w1  = (const float*)d_in[11];
  const float* b1  = (const float*)d_in[12];
  const float* w2  = (const float*)d_in[13];
  const float* b2  = (const float*)d_in[14];
  const float* wgw = (const float*)d_in[15];
  const float* bgw = (const float*)d_in[16];
  const float* wgt = (const float*)d_in[17];
  const float* bgt = (const float*)d_in[18];

  const int E2 = in_sizes[0]/128;
  const int Nn = in_sizes[1]/128;
  const int E1 = in_sizes[5];
  const int* src2 = ei2;
  const int* dst2 = ei2 + E2;

  // workspace carve (16B-aligned regions, ~76 MB)
  char* p = (char*)d_ws;
  u16* Q1 = (u16*)p;       p += (size_t)E2*128*2;
  u16* Q2 = (u16*)p;       p += (size_t)E2*128*2;
  u16* P3 = (u16*)p;       p += (size_t)E2*128*2;   // aliased as S after wedge
  u16* rbf1p = (u16*)p;    p += (size_t)E2*32*2;
  u16* Hout  = (u16*)p;    p += (size_t)3*Nn*128*2; // Hi | Hk | Hj
  u16* Wall  = (u16*)p;    p += (size_t)110592*2;
  u16* WcT   = (u16*)p;    p += (size_t)128*128*2;
  u16* WgtT  = (u16*)p;    p += (size_t)128*128*2;
  float* sph_c = (float*)p; p += (size_t)E2*4;
  float* bc2   = (float*)p; p += 512;
  int* out_ptr = (int*)p;   p += (((size_t)(Nn+1)*4 + 63)/64)*64;
  int* cnt     = (int*)p;   p += (size_t)E2*4;
  u16* S = P3;   // alias: safe (row-local read-then-write in k_wedge)
  u16* Hi = Hout, *Hk = Hout + (size_t)Nn*128, *Hj = Hout + (size_t)2*Nn*128;

  // fused setup: block-range dispatch
  const int nb_edges = (E1+255)/256;
  const int nb_ptr   = (Nn+1+255)/256;
  const int nb_w     = (110592+255)/256;
  const int nb_small = (16512+255)/256;
  const int nb0 = nb_edges;
  const int nb1 = nb0 + nb_ptr;
  const int nb2 = nb1 + nb_w;
  const int nbT = nb2 + nb_small;
  k_setup_all<<<nbT, 256, 0, stream>>>(e1_to_e2, rbf_e1, sph_e1, rbf1p, sph_c, E1,
                                       src2, out_ptr, Nn, E2,
                                       w1, Wall, w2, wgw, wgt, b2,
                                       WcT, WgtT, bc2,
                                       nb0, nb1, nb2);

  const int Mh = (Nn+127)/128;
  k_gemmH<<<dim3(Mh,3), 256, 0, stream>>>(h, Wall + 61440, Hout, Nn);

  const int Mb = (E2+127)/128;
  {
    GArgs a = {};
    a.t_f32=t_e2; a.rbf_e2=rbf_e2; a.rbf1p=rbf1p;
    a.src2=src2; a.dst2=dst2;
    a.B0=Wall; a.B1=Wall+20480; a.B2=Wall+40960;
    a.Hi=Hi; a.Hk=Hk; a.Hj=Hj; a.b1=b1;
    a.out0=Q1; a.out1=Q2; a.out2=P3; a.M=E2;
    k_gemm0<<<Mb*3, 256, 0, stream>>>(a);
  }
  k_wedge<<<(E2+3)/4, 256, 0, stream>>>(src2, dst2, out_ptr, sph_c,
                                        Q1, Q2, P3, w1, S, cnt, E2);
  {
    GArgs a = {};
    a.Asrc=S; a.cnt=cnt; a.Bmat=WcT; a.Bmat2=WgtT;
    a.bgw=bgw; a.bgt=bgt; a.bc2=bc2; a.t_f32=t_e2;
    a.outf=(float*)d_out; a.M=E2;
    k_gemm12<<<Mb, 256, 0, stream>>>(a);
  }
}

// Round 10
// 298.060 us; speedup vs baseline: 1.1099x; 1.0610x over previous
//
#include <hip/hip_runtime.h>
#include <math.h>

typedef unsigned short u16;
typedef unsigned int u32;
typedef __bf16 bf16x8 __attribute__((ext_vector_type(8)));
typedef float f32x4 __attribute__((ext_vector_type(4)));

__device__ __forceinline__ float bf2f(u16 v){ union{u32 u;float f;}c; c.u=((u32)v)<<16; return c.f; }
__device__ __forceinline__ u16 f2bf(float f){ union{__bf16 h; u16 u;}c; c.h=(__bf16)f; return c.u; }
__device__ __forceinline__ u32 pk2(float a, float b){
  union{ __bf16 h[2]; u32 u; }c; c.h[0]=(__bf16)a; c.h[1]=(__bf16)b; return c.u;
}
// load 8 consecutive f32 (32B-aligned) -> 8 bf16 packed in uint4
__device__ __forceinline__ uint4 ld8f(const float* p){
  float4 x = ((const float4*)p)[0];
  float4 y = ((const float4*)p)[1];
  uint4 r; r.x=pk2(x.x,x.y); r.y=pk2(x.z,x.w); r.z=pk2(y.x,y.y); r.w=pk2(y.z,y.w);
  return r;
}
// silu via v_rcp_f32 (1-ulp) instead of IEEE divide
__device__ __forceinline__ float fsilu(float x){
  return x*__builtin_amdgcn_rcpf(1.f+__expf(-x));
}

// ---------------- fused setup kernel ----------------
// ranges: [0,nb0) edges | [nb0,nb1) out_ptr | [nb1,nb2) weights | [nb2,..) smallw
// Wall layout (u16):
//   [0)      W0T[128][160]: k<128 -> w1 row k     (t1) | k>=128 -> 768+(k-128) (rbf1_ik)
//   [20480)  W1T[128][160]: k<128 -> 128+k        (t2) | k>=128 -> 800+(k-128) (rbf1_kj)
//   [40960)  W2T[128][160]: k<128 -> 256+k        (t3) | k>=128 -> 832+(k-128) (rbf2)
//   [61440)  WHiT[128][128]: [n][k] = w1[(384+k)*128+n]
//   [77824)  WHkT[128][128]: [n][k] = w1[(512+k)*128+n]
//   [94208)  WHjT[128][128]: [n][k] = w1[(640+k)*128+n]
__global__ void k_setup_all(const int* __restrict__ e1_to_e2,
                            const float* __restrict__ rbf_e1,
                            const float* __restrict__ sph_e1,
                            u16* __restrict__ rbf1p, float* __restrict__ sph_c, int E1,
                            const int* __restrict__ src2, int* __restrict__ out_ptr,
                            int Nn, int E2,
                            const float* __restrict__ w1, u16* __restrict__ Wall,
                            const float* __restrict__ w2, const float* __restrict__ wgw,
                            const float* __restrict__ wgt, const float* __restrict__ b2,
                            u16* __restrict__ WcT, u16* __restrict__ WgtT,
                            float* __restrict__ bc2,
                            int nb0, int nb1, int nb2) {
  const int b = blockIdx.x, t = threadIdx.x;
  if (b < nb0) {
    int e = b*256 + t;
    if (e >= E1) return;
    int f = e1_to_e2[e];
    sph_c[f] = sph_e1[e*3+1];
    const float* s = rbf_e1 + (size_t)e*32;
    uint4* d = (uint4*)(rbf1p + (size_t)f*32);
    d[0]=ld8f(s); d[1]=ld8f(s+8); d[2]=ld8f(s+16); d[3]=ld8f(s+24);
  } else if (b < nb1) {
    int n = (b-nb0)*256 + t;
    if (n > Nn) return;
    int lo=0, hi=E2;
    while (lo<hi){ int m=(lo+hi)>>1; if (src2[m]<n) lo=m+1; else hi=m; }
    out_ptr[n]=lo;
  } else if (b < nb2) {
    int id = (b-nb1)*256 + t;
    if (id < 61440) {
      int m = id / 20480;
      int r2 = id - m*20480;
      int n = r2 / 160, k = r2 - n*160;
      int row;
      if (m==0)      row = (k<128)? k       : 768+(k-128);
      else if (m==1) row = (k<128)? 128+k   : 800+(k-128);
      else           row = (k<128)? 256+k   : 832+(k-128);
      Wall[id] = f2bf(w1[row*128+n]);
    } else if (id < 110592) {
      int idh = id - 61440;
      int m = idh >> 14;            // 0..2
      int r2 = idh & 16383;
      int n = r2 >> 7, k = r2 & 127;
      int base = 384 + m*128;
      Wall[id] = f2bf(w1[(base+k)*128+n]);
    }
  } else {
    int id = (b-nb2)*256 + t;
    if (id < 16384) {
      int n = id&127, k = id>>7;
      float s = 0.f;
      for (int r=0;r<128;r++) s += w2[k*128+r]*wgw[r*128+n];
      WcT[n*128+k] = f2bf(s);
      WgtT[n*128+k] = f2bf(wgt[k*128+n]);
    } else if (id < 16384+128) {
      int n = id-16384;
      float s = 0.f;
      for (int r=0;r<128;r++) s += b2[r]*wgw[r*128+n];
      bc2[n] = s;
    }
  }
}

// ---------------- per-node h projection: H{i,k,j} = h @ WH{i,k,j} ----------------
__global__ __launch_bounds__(256, 2)
void k_gemmH(const float* __restrict__ h, const u16* __restrict__ WH,
             u16* __restrict__ Hout, int Nn) {
  const int bm = blockIdx.x, bn = blockIdx.y;
  const u16* Bp = WH + bn*16384;
  u16* dst = Hout + (size_t)bn*Nn*128;
  __shared__ u16 As[128*40];
  __shared__ u16 Bs[128*40];
  const int tid = threadIdx.x;
  const int lane = tid & 63, wave = tid >> 6;
  const int wm = wave >> 1, wn = wave & 1;
  const int quad = lane >> 4, l16 = lane & 15;
  const int part = tid & 3;
  const int ra = tid >> 2;
  const int rb = ra + 64;
  long fa = (long)bm*128 + ra; if (fa >= Nn) fa = Nn-1;
  long fb = (long)bm*128 + rb; if (fb >= Nn) fb = Nn-1;

  f32x4 acc[4][4] = {};
  for (int ks=0; ks<4; ks++) {
    const int kb = ks*32;
    uint4 va = ld8f(h + fa*128 + kb + part*8);
    uint4 vb = ld8f(h + fb*128 + kb + part*8);
    uint4 wa = *(const uint4*)(Bp + (long)ra*128 + kb + part*8);
    uint4 wb = *(const uint4*)(Bp + (long)rb*128 + kb + part*8);
    __syncthreads();
    *(uint4*)(As + ra*40 + part*8) = va;
    *(uint4*)(As + rb*40 + part*8) = vb;
    *(uint4*)(Bs + ra*40 + part*8) = wa;
    *(uint4*)(Bs + rb*40 + part*8) = wb;
    __syncthreads();
    bf16x8 af[4], bfr[4];
    #pragma unroll
    for (int t=0;t<4;t++) {
      af[t]  = *(const bf16x8*)(As + (wm*64 + t*16 + l16)*40 + quad*8);
      bfr[t] = *(const bf16x8*)(Bs + (wn*64 + t*16 + l16)*40 + quad*8);
    }
    #pragma unroll
    for (int tm=0;tm<4;tm++)
      #pragma unroll
      for (int tn=0;tn<4;tn++)
        acc[tm][tn] = __builtin_amdgcn_mfma_f32_16x16x32_bf16(af[tm], bfr[tn], acc[tm][tn], 0,0,0);
  }
  #pragma unroll
  for (int tm=0;tm<4;tm++) {
    const int rloc = wm*64 + tm*16 + quad*4;
    #pragma unroll
    for (int r=0;r<4;r++) {
      long row = (long)bm*128 + rloc + r;
      if (row >= Nn) continue;
      #pragma unroll
      for (int tn=0;tn<4;tn++) {
        const int col = wn*64 + tn*16 + l16;
        dst[row*128 + col] = f2bf(acc[tm][tn][r]);
      }
    }
  }
}

// ---------------- fused wedge enumeration + accumulation + H-add ----------------
// one wave per e2 edge gw=(i,j). lanes 0..7 search the 8 out-edge candidates;
// ballot -> uniform mask. Per-wave base folds P3[gw] + Hi[i] + Hj[j] (i,j fixed
// per gw). Per-wedge slot gathers Q1[f], Q2[lo], Hk[k] (k=dst2[f]); processed in
// two 4-slot batches to keep peak VGPR <=64 (no spill at occupancy 8).
__global__ __launch_bounds__(256, 8)
void k_wedge(const int* __restrict__ src2, const int* __restrict__ dst2,
             const int* __restrict__ out_ptr, const float* __restrict__ sph_c,
             const u16* __restrict__ Q1, const u16* __restrict__ Q2,
             const u16* __restrict__ P3, const float* __restrict__ w1,
             const u16* __restrict__ Hi, const u16* __restrict__ Hk,
             const u16* __restrict__ Hj,
             u16* __restrict__ S, int* __restrict__ cnt, int E2) {
  int gw = (int)((blockIdx.x*256 + threadIdx.x) >> 6);
  int lane = threadIdx.x & 63;
  if (gw >= E2) return;
  int i = src2[gw], j = dst2[gw];
  // issue per-wave row loads early (latency hides under the search)
  u32 hiu = ((const u32*)(Hi + (size_t)(u32)i*128))[lane];
  u32 hju = ((const u32*)(Hj + (size_t)(u32)j*128))[lane];
  u32 p3u = ((const u32*)(P3 + (size_t)gw*128))[lane];
  float2 wv = ((const float2*)(w1 + 864*128))[lane];

  int f = 0, lo = 0, kk = 0; float cf = 0.f; bool valid = false;
  if (lane < 8) {
    int ff = out_ptr[i] + lane;
    if (ff < out_ptr[i+1]) {
      int k = dst2[ff];
      int l = out_ptr[k], hh = out_ptr[k+1], h0 = hh;
      while (l<hh){ int m=(l+hh)>>1; if (dst2[m]<j) l=m+1; else hh=m; }
      if (l<h0 && dst2[l]==j){ valid=true; f=ff; lo=l; kk=k; cf=sph_c[ff]*sph_c[l]; }
    }
  }
  unsigned long long mask = __ballot(valid);
  const int nw = __popcll(mask);
  if (lane==0) cnt[gw] = nw;

  const float base0 = bf2f((u16)(p3u&0xffff)) + bf2f((u16)(hiu&0xffff)) + bf2f((u16)(hju&0xffff));
  const float base1 = bf2f((u16)(p3u>>16))    + bf2f((u16)(hiu>>16))    + bf2f((u16)(hju>>16));
  const u32* q1b = (const u32*)Q1;
  const u32* q2b = (const u32*)Q2;
  const u32* hkb = (const u32*)Hk;

  float a0=0.f, a1=0.f;
  unsigned long long m2 = mask;
  #pragma unroll
  for (int half=0; half<2; half++) {
    const int base = half*4;
    u32 xa[4], ya[4], za[4]; float ca[4];
    #pragma unroll
    for (int s=0; s<4; s++) {
      if (base+s < nw) {
        int b = __ffsll((long long)m2)-1; m2 &= m2-1;
        int fA = __builtin_amdgcn_readlane(f, b);
        int lA = __builtin_amdgcn_readlane(lo, b);
        int kA = __builtin_amdgcn_readlane(kk, b);
        ca[s] = __int_as_float(__builtin_amdgcn_readlane(__float_as_int(cf), b));
        xa[s] = q1b[((size_t)(u32)fA<<6) + lane];
        ya[s] = q2b[((size_t)(u32)lA<<6) + lane];
        za[s] = hkb[((size_t)(u32)kA<<6) + lane];
      }
    }
    #pragma unroll
    for (int s=0; s<4; s++) {
      if (base+s < nw) {
        float b0 = fmaf(ca[s], wv.x, base0);
        float b1 = fmaf(ca[s], wv.y, base1);
        float x0 = b0 + bf2f((u16)(xa[s]&0xffff)) + bf2f((u16)(ya[s]&0xffff)) + bf2f((u16)(za[s]&0xffff));
        float x1 = b1 + bf2f((u16)(xa[s]>>16))    + bf2f((u16)(ya[s]>>16))    + bf2f((u16)(za[s]>>16));
        a0 += fsilu(x0);
        a1 += fsilu(x1);
      }
    }
  }
  ((u32*)(S + (size_t)gw*128))[lane] = pk2(a0, a1);
}

// ---------------- GEMM args ----------------
struct GArgs {
  const float* t_f32; const float* rbf_e2;
  const u16* rbf1p; const u16* Asrc;
  const int* cnt;
  const u16* B0; const u16* B1; const u16* B2;
  const u16* Bmat; const u16* Bmat2;
  const float* b1; const float* bgw; const float* bgt; const float* bc2;
  u16* out0; u16* out1; u16* out2;
  float* outf;
  int M;
};

// ---------------- big GEMM: uniform K=160, trivial epilogue ----------------
// bn=0: [t|rbf1]@W0 -> Q1' (H added in k_wedge)
// bn=1: [t|rbf1]@W1 -> Q2'
// bn=2: [t|rbf2]@W2 + b1 -> P3
// Round-4 proven 2-barrier staged loop, 20 KB LDS, XCD-swizzled grid.
__global__ __launch_bounds__(256, 2)
void k_gemm0(GArgs a) {
  const int nwg = gridDim.x;
  const int id  = blockIdx.x;
  const int xcd = id & 7, idx = id >> 3;
  const int q = nwg >> 3, r = nwg & 7;
  const int w = (xcd < r ? xcd*(q+1) : r*(q+1) + (xcd-r)*q) + idx;
  const int bm = w/3, bn = w - bm*3;

  __shared__ u16 As[128*40];
  __shared__ u16 Bs[128*40];
  const int tid = threadIdx.x;
  const int lane = tid & 63, wave = tid >> 6;
  const int wm = wave >> 1, wn = wave & 1;
  const int quad = lane >> 4, l16 = lane & 15;

  const int part = tid & 3;        // k-subchunk (8 elems)
  const int ra = tid >> 2;
  const int rb = ra + 64;
  long fa = (long)bm*128 + ra;
  long fb = (long)bm*128 + rb;
  if (fa >= a.M) fa = a.M-1;
  if (fb >= a.M) fb = a.M-1;

  const u16* Bp = (bn==0)? a.B0 : (bn==1)? a.B1 : a.B2;
  constexpr int KT = 160;

  f32x4 acc[4][4] = {};
  for (int ks=0; ks<5; ks++) {
    const int kb = ks*32;
    uint4 va, vb;
    if (ks<4)        { va = ld8f(a.t_f32 + fa*128 + kb + part*8);
                       vb = ld8f(a.t_f32 + fb*128 + kb + part*8); }
    else if (bn<2)   { va = *(const uint4*)(a.rbf1p + fa*32 + part*8);
                       vb = *(const uint4*)(a.rbf1p + fb*32 + part*8); }
    else             { va = ld8f(a.rbf_e2 + fa*32 + part*8);
                       vb = ld8f(a.rbf_e2 + fb*32 + part*8); }
    uint4 wa = *(const uint4*)(Bp + (long)ra*KT + kb + part*8);
    uint4 wb = *(const uint4*)(Bp + (long)rb*KT + kb + part*8);
    __syncthreads();
    *(uint4*)(As + ra*40 + part*8) = va;
    *(uint4*)(As + rb*40 + part*8) = vb;
    *(uint4*)(Bs + ra*40 + part*8) = wa;
    *(uint4*)(Bs + rb*40 + part*8) = wb;
    __syncthreads();
    bf16x8 af[4], bfr[4];
    #pragma unroll
    for (int t=0;t<4;t++) {
      af[t]  = *(const bf16x8*)(As + (wm*64 + t*16 + l16)*40 + quad*8);
      bfr[t] = *(const bf16x8*)(Bs + (wn*64 + t*16 + l16)*40 + quad*8);
    }
    #pragma unroll
    for (int tm=0;tm<4;tm++)
      #pragma unroll
      for (int tn=0;tn<4;tn++)
        acc[tm][tn] = __builtin_amdgcn_mfma_f32_16x16x32_bf16(af[tm], bfr[tn], acc[tm][tn], 0,0,0);
  }

  // epilogue (C/D: col=lane&15, row=quad*4+reg)
  u16* dst = (bn==0)? a.out0 : (bn==1)? a.out1 : a.out2;
  #pragma unroll
  for (int tm=0;tm<4;tm++) {
    const int rloc = wm*64 + tm*16 + quad*4;
    #pragma unroll
    for (int r=0;r<4;r++) {
      long row = (long)bm*128 + rloc + r;
      if (row >= a.M) continue;
      #pragma unroll
      for (int tn=0;tn<4;tn++) {
        const int col = wn*64 + tn*16 + l16;
        float v = acc[tm][tn][r];
        if (bn==2) v += a.b1[col];
        dst[row*128 + col] = f2bf(v);
      }
    }
  }
}

// ---------------- fused gate GEMMs (round-4 proven structure) ----------------
__global__ __launch_bounds__(256, 2)
void k_gemm12(GArgs a) {
  __shared__ u16 As[128*40];
  __shared__ u16 Bs[128*40];
  const int tid = threadIdx.x;
  const int bm = blockIdx.x;
  const int lane = tid & 63, wave = tid >> 6;
  const int wm = wave >> 1, wn = wave & 1;
  const int quad = lane >> 4, l16 = lane & 15;

  const int part = tid & 3;
  const int ra = tid >> 2;
  const int rb = ra + 64;
  long fa = (long)bm*128 + ra;
  long fb = (long)bm*128 + rb;
  if (fa >= a.M) fa = a.M-1;
  if (fb >= a.M) fb = a.M-1;

  f32x4 acc1[4][4] = {};
  f32x4 acc2[4][4] = {};
  // pass 1: S @ WcT
  for (int ks=0; ks<4; ks++) {
    const int kb = ks*32;
    uint4 va = *(const uint4*)(a.Asrc + fa*128 + kb + part*8);
    uint4 vb = *(const uint4*)(a.Asrc + fb*128 + kb + part*8);
    uint4 wa = *(const uint4*)(a.Bmat + (long)ra*128 + kb + part*8);
    uint4 wbv= *(const uint4*)(a.Bmat + (long)rb*128 + kb + part*8);
    __syncthreads();
    *(uint4*)(As + ra*40 + part*8) = va;
    *(uint4*)(As + rb*40 + part*8) = vb;
    *(uint4*)(Bs + ra*40 + part*8) = wa;
    *(uint4*)(Bs + rb*40 + part*8) = wbv;
    __syncthreads();
    bf16x8 af[4], bfr[4];
    #pragma unroll
    for (int t=0;t<4;t++) {
      af[t]  = *(const bf16x8*)(As + (wm*64 + t*16 + l16)*40 + quad*8);
      bfr[t] = *(const bf16x8*)(Bs + (wn*64 + t*16 + l16)*40 + quad*8);
    }
    #pragma unroll
    for (int tm=0;tm<4;tm++)
      #pragma unroll
      for (int tn=0;tn<4;tn++)
        acc1[tm][tn] = __builtin_amdgcn_mfma_f32_16x16x32_bf16(af[tm], bfr[tn], acc1[tm][tn], 0,0,0);
  }
  // pass 2: bf16(t) @ WgtT
  for (int ks=0; ks<4; ks++) {
    const int kb = ks*32;
    uint4 va = ld8f(a.t_f32 + fa*128 + kb + part*8);
    uint4 vb = ld8f(a.t_f32 + fb*128 + kb + part*8);
    uint4 wa = *(const uint4*)(a.Bmat2 + (long)ra*128 + kb + part*8);
    uint4 wbv= *(const uint4*)(a.Bmat2 + (long)rb*128 + kb + part*8);
    __syncthreads();
    *(uint4*)(As + ra*40 + part*8) = va;
    *(uint4*)(As + rb*40 + part*8) = vb;
    *(uint4*)(Bs + ra*40 + part*8) = wa;
    *(uint4*)(Bs + rb*40 + part*8) = wbv;
    __syncthreads();
    bf16x8 af[4], bfr[4];
    #pragma unroll
    for (int t=0;t<4;t++) {
      af[t]  = *(const bf16x8*)(As + (wm*64 + t*16 + l16)*40 + quad*8);
      bfr[t] = *(const bf16x8*)(Bs + (wn*64 + t*16 + l16)*40 + quad*8);
    }
    #pragma unroll
    for (int tm=0;tm<4;tm++)
      #pragma unroll
      for (int tn=0;tn<4;tn++)
        acc2[tm][tn] = __builtin_amdgcn_mfma_f32_16x16x32_bf16(af[tm], bfr[tn], acc2[tm][tn], 0,0,0);
  }

  // combined epilogue (rcp-based sigmoid/tanh; 1-ulp, within tolerance)
  #pragma unroll
  for (int tm=0;tm<4;tm++) {
    const int rloc = wm*64 + tm*16 + quad*4;
    #pragma unroll
    for (int r=0;r<4;r++) {
      long row = (long)bm*128 + rloc + r;
      if (row >= a.M) continue;
      #pragma unroll
      for (int tn=0;tn<4;tn++) {
        const int col = wn*64 + tn*16 + l16;
        float u = acc1[tm][tn][r] + (float)a.cnt[row]*a.bc2[col] + a.bgw[col];
        float g = __builtin_amdgcn_rcpf(1.f+__expf(-u));
        float vv = acc2[tm][tn][r] + a.bgt[col];
        float th = 1.f - 2.f*__builtin_amdgcn_rcpf(__expf(2.f*vv)+1.f);
        float t  = a.t_f32[row*128+col];
        a.outf[row*128+col] = t + g*th;
      }
    }
  }
}

// ---------------- launch ----------------
extern "C" void kernel_launch(void* const* d_in, const int* in_sizes, int n_in,
                              void* d_out, int out_size, void* d_ws, size_t ws_size,
                              hipStream_t stream) {
  const float* t_e2  = (const float*)d_in[0];
  const float* h     = (const float*)d_in[1];
  const int* ei2     = (const int*)d_in[3];
  const int* e1_to_e2 = (const int*)d_in[4];
  const float* rbf_e1 = (const float*)d_in[7];
  const float* rbf_e2 = (const float*)d_in[8];
  const float* sph_e1 = (const float*)d_in[9];
  const float* w1  = (const float*)d_in[11];
  const float* b1  = (const float*)d_in[12];
  const float* w2  = (const float*)d_in[13];
  const float* b2  = (const float*)d_in[14];
  const float* wgw = (const float*)d_in[15];
  const float* bgw = (const float*)d_in[16];
  const float* wgt = (const float*)d_in[17];
  const float* bgt = (const float*)d_in[18];

  const int E2 = in_sizes[0]/128;
  const int Nn = in_sizes[1]/128;
  const int E1 = in_sizes[5];
  const int* src2 = ei2;
  const int* dst2 = ei2 + E2;

  // workspace carve (16B-aligned regions, ~76 MB)
  char* p = (char*)d_ws;
  u16* Q1 = (u16*)p;       p += (size_t)E2*128*2;
  u16* Q2 = (u16*)p;       p += (size_t)E2*128*2;
  u16* P3 = (u16*)p;       p += (size_t)E2*128*2;   // aliased as S after wedge
  u16* rbf1p = (u16*)p;    p += (size_t)E2*32*2;
  u16* Hout  = (u16*)p;    p += (size_t)3*Nn*128*2; // Hi | Hk | Hj
  u16* Wall  = (u16*)p;    p += (size_t)110592*2;
  u16* WcT   = (u16*)p;    p += (size_t)128*128*2;
  u16* WgtT  = (u16*)p;    p += (size_t)128*128*2;
  float* sph_c = (float*)p; p += (size_t)E2*4;
  float* bc2   = (float*)p; p += 512;
  int* out_ptr = (int*)p;   p += (((size_t)(Nn+1)*4 + 63)/64)*64;
  int* cnt     = (int*)p;   p += (size_t)E2*4;
  u16* S = P3;   // alias: safe (row-local read-then-write in k_wedge)
  u16* Hi = Hout, *Hk = Hout + (size_t)Nn*128, *Hj = Hout + (size_t)2*Nn*128;

  // fused setup: block-range dispatch
  const int nb_edges = (E1+255)/256;
  const int nb_ptr   = (Nn+1+255)/256;
  const int nb_w     = (110592+255)/256;
  const int nb_small = (16512+255)/256;
  const int nb0 = nb_edges;
  const int nb1 = nb0 + nb_ptr;
  const int nb2 = nb1 + nb_w;
  const int nbT = nb2 + nb_small;
  k_setup_all<<<nbT, 256, 0, stream>>>(e1_to_e2, rbf_e1, sph_e1, rbf1p, sph_c, E1,
                                       src2, out_ptr, Nn, E2,
                                       w1, Wall, w2, wgw, wgt, b2,
                                       WcT, WgtT, bc2,
                                       nb0, nb1, nb2);

  const int Mh = (Nn+127)/128;
  k_gemmH<<<dim3(Mh,3), 256, 0, stream>>>(h, Wall + 61440, Hout, Nn);

  const int Mb = (E2+127)/128;
  {
    GArgs a = {};
    a.t_f32=t_e2; a.rbf_e2=rbf_e2; a.rbf1p=rbf1p;
    a.B0=Wall; a.B1=Wall+20480; a.B2=Wall+40960;
    a.b1=b1;
    a.out0=Q1; a.out1=Q2; a.out2=P3; a.M=E2;
    k_gemm0<<<Mb*3, 256, 0, stream>>>(a);
  }
  k_wedge<<<(E2+3)/4, 256, 0, stream>>>(src2, dst2, out_ptr, sph_c,
                                        Q1, Q2, P3, w1, Hi, Hk, Hj, S, cnt, E2);
  {
    GArgs a = {};
    a.Asrc=S; a.cnt=cnt; a.Bmat=WcT; a.Bmat2=WgtT;
    a.bgw=bgw; a.bgt=bgt; a.bc2=bc2; a.t_f32=t_e2;
    a.outf=(float*)d_out; a.M=E2;
    k_gemm12<<<Mb, 256, 0, stream>>>(a);
  }
}